// Round 15
// baseline (27.642 us; speedup 1.0000x reference)
//
#include <hip/hip_runtime.h>
#include <float.h>
#include <math.h>

// Problem constants (fixed by reference)
#define NB    8
#define K1    2048
#define K2    8192
#define NADD  16
#define PP    128          // K1 / NUM_ADD
#define FEPS  1e-7f
#define CDW   0.1f

// Kernel A: 64 farthest + 512 chamfer blocks (b x 64 rowblks of 32 rows).
// Chamfer block stages ALL 8192 ori pts of its batch packed in 64 KB LDS
// (one phase) -> exactly 2 blocks/CU resident.
#define FAR_GRID 64
#define CH_GRID  (NB * 64)            // 512
#define GRID_A   (FAR_GRID + CH_GRID) // 576

// Kernel B: 64 reduce blocks + last-done combine (proven pattern)
#define RB_GRID  64

// ws layout (float offsets)
#define PMIN_OFF  0                       // [NB][K1] = 16384 floats (64 KB)
#define FARW_OFF  16384                   // 128 floats
#define CHB_OFF   (FARW_OFF + NB * NADD)  // 64 floats
#define CTR_OFF   (CHB_OFF + 64)

typedef __bf16 bf16x8 __attribute__((ext_vector_type(8)));
typedef float  f32x16 __attribute__((ext_vector_type(16)));
typedef unsigned long long u64;

// fp32 -> bf16 bits, round-to-nearest-even (proven R11-R13, absmax 0)
__device__ __forceinline__ u64 bfbits(float x) {
    union { float f; unsigned int u; } c; c.f = x;
    unsigned int u = c.u;
    u += 0x7fffu + ((u >> 16) & 1u);
    return (u64)(u >> 16);
}
__device__ __forceinline__ u64 pack3(float x, float y, float z) {
    float o2 = fmaf(x, x, fmaf(y, y, z * z));
    return bfbits(x) | (bfbits(y) << 16) | (bfbits(z) << 32) | (bfbits(o2) << 48);
}

// ---------------------------------------------------------------------------
// Kernel A: farthest (blocks 0..63, exact fp32) + MFMA chamfer (64..575).
// Chamfer block = (b, rowblk of 32 adv rows):
//   - stage+pack all 8192 ori pts of batch b into 64 KB LDS (one pass)
//   - each wave: 64 tiles of 32 ori pts vs the block's 32 rows via one
//     v_mfma_f32_32x32x16_bf16 per tile (replicated fragments, 1/4 scale --
//     R13-verified: acc = o^2 - 2 a.o under any K map), then 16 v_min
//   - 5-step col butterfly + cross-wave LDS min -> pmins[b][row] (complete)
// C layout (m74/m101): col = lane&31, row = (r&3) + 8*(r>>2) + 4*(lane>>5).
// ---------------------------------------------------------------------------
__global__ __launch_bounds__(256) void fused_a(const float* __restrict__ adv,
                                               const float* __restrict__ ori,
                                               float* __restrict__ pmins,
                                               float* __restrict__ farw,
                                               unsigned int* __restrict__ ctr) {
    __shared__ u64 so[K2];             // 64 KB; far path reuses as float[768]
    __shared__ float smin[4][32];
    __shared__ float sred[4];
    const int bid = blockIdx.x;
    const int t   = threadIdx.x;
    if (bid == 0 && t == 0) *ctr = 0u;    // reset kernel-B counter (B runs after A)

    if (bid < FAR_GRID) {
        // ---- farthest: block = (b, cluster-pair), 128 threads per cluster ----
        const int b  = bid >> 3;
        const int cp = bid & 7;
        const int g  = t >> 7;
        const int p  = t & 127;
        const int ci = cp * 2 + g;

        float* sf = (float*)so;        // [2][3][128]
        const float* c = adv + (size_t)(b * K1 + ci * PP) * 3;
        float px = c[p * 3 + 0], py = c[p * 3 + 1], pz = c[p * 3 + 2];
        float* sx = sf + g * 384;
        sx[p] = px; sx[128 + p] = py; sx[256 + p] = pz;
        __syncthreads();

        const float pxm = px - FEPS, pym = py - FEPS, pzm = pz - FEPS;
        float mx = 0.f;
#pragma unroll 8
        for (int q = 0; q < PP; ++q) {
            float dx = sx[q] - pxm;
            float dy = sx[128 + q] - pym;
            float dz = sx[256 + q] - pzm;
            mx = fmaxf(mx, fmaf(dx, dx, fmaf(dy, dy, dz * dz)));
        }
#pragma unroll
        for (int off = 32; off; off >>= 1) mx = fmaxf(mx, __shfl_down(mx, off, 64));
        if ((t & 63) == 0) sred[t >> 6] = mx;
        __syncthreads();
        if (t == 0)   farw[b * NADD + cp * 2 + 0] = sqrtf(fmaxf(sred[0], sred[1]));
        if (t == 128) farw[b * NADD + cp * 2 + 1] = sqrtf(fmaxf(sred[2], sred[3]));
    } else {
        // ---- chamfer: block = (b, rowblk) vs ALL ori of batch b ----
        const int cb   = bid - FAR_GRID;
        const int rowb = (cb & 63) * 32;
        const int b    = cb >> 6;
        const int lane = t & 63;
        const int wv   = t >> 6;
        const int col  = lane & 31;

        // stage+pack: 2048 groups of 4 pts; 8 groups/thread (3 float4 -> 4 u64)
        const float4* f4 = (const float4*)(ori + (size_t)b * K2 * 3);
#pragma unroll
        for (int i = 0; i < 8; ++i) {
            const int pg = i * 256 + t;
            float4 f0 = f4[pg * 3 + 0];
            float4 f1 = f4[pg * 3 + 1];
            float4 f2 = f4[pg * 3 + 2];
            u64 w0 = pack3(f0.x, f0.y, f0.z);
            u64 w1 = pack3(f0.w, f1.x, f1.y);
            u64 w2 = pack3(f1.z, f1.w, f2.x);
            u64 w3 = pack3(f2.y, f2.z, f2.w);
            ulonglong2* dst = (ulonglong2*)&so[pg * 4];
            dst[0] = make_ulonglong2(w0, w1);
            dst[1] = make_ulonglong2(w2, w3);
        }

        // A fragment: row = col, quad replicated, 1/4 scale
        const float* a0 = adv + ((size_t)b * K1 + rowb + col) * 3;
        u64 q = bfbits(-0.5f * a0[0]) | (bfbits(-0.5f * a0[1]) << 16)
              | (bfbits(-0.5f * a0[2]) << 32) | (0x3e80ULL << 48);  // bf16(0.25)
        const bf16x8 af = __builtin_bit_cast(bf16x8, make_ulonglong2(q, q));
        __syncthreads();

        const f32x16 z16 = {};
        f32x16 m;
#pragma unroll
        for (int r = 0; r < 16; ++r) m[r] = FLT_MAX;

        // this wave: 2048 pts = 64 tiles of 32 (2-way bcast, 2-way bank: free)
#pragma unroll 4
        for (int tl = 0; tl < 64; ++tl) {
            u64 lo = so[wv * 2048 + tl * 32 + col];
            bf16x8 bf = __builtin_bit_cast(bf16x8, make_ulonglong2(lo, lo));
            f32x16 acc = __builtin_amdgcn_mfma_f32_32x32x16_bf16(af, bf, z16, 0, 0, 0);
#pragma unroll
            for (int r = 0; r < 16; ++r) m[r] = fminf(m[r], acc[r]);
        }

        // min over 32 cols: butterfly on lane&31; rows land per C layout
#pragma unroll
        for (int r = 0; r < 16; ++r) {
            float v = m[r];
#pragma unroll
            for (int msk = 1; msk < 32; msk <<= 1) v = fminf(v, __shfl_xor(v, msk, 64));
            if (col == 0)
                smin[wv][(r & 3) + 8 * (r >> 2) + 4 * (lane >> 5)] = v;
        }
        __syncthreads();

        if (t < 32) {
            float mm = fminf(fminf(smin[0][t], smin[1][t]),
                             fminf(smin[2][t], smin[3][t]));
            pmins[(size_t)b * K1 + rowb + t] = mm;   // complete per-row min
        }
    }
}

// ---------------------------------------------------------------------------
// Kernel B: a^2 + clamp + per-(b,kc) sum over complete row-mins; last-done
// block does the final weighted combine (proven pattern, 64 returned RMWs).
// ---------------------------------------------------------------------------
__global__ __launch_bounds__(256) void reduce_b(const float* __restrict__ adv,
                                                const float* __restrict__ pmins,
                                                const float* __restrict__ farw,
                                                const float* __restrict__ w,
                                                float* __restrict__ chbp,
                                                unsigned int* __restrict__ ctr,
                                                float* __restrict__ out) {
    __shared__ float s[4];
    __shared__ unsigned int lastflag;
    const int t  = threadIdx.x;
    const int kc = blockIdx.x & 7;
    const int b  = blockIdx.x >> 3;
    const int k  = kc * 256 + t;

    float m = pmins[(size_t)b * K1 + k];
    const float* a = adv + ((size_t)b * K1 + k) * 3;
    float a2 = fmaf(a[0], a[0], fmaf(a[1], a[1], a[2] * a[2]));
    float sum = fmaxf(a2 + m, 0.f);          // clamp commutes with min

#pragma unroll
    for (int off = 32; off; off >>= 1) sum += __shfl_down(sum, off, 64);
    const int lane = t & 63, wid = t >> 6;
    if (lane == 0) s[wid] = sum;
    __syncthreads();

    if (t == 0) {
        float part = s[0] + s[1] + s[2] + s[3];
        __hip_atomic_store(&chbp[b * 8 + kc], part,
                           __ATOMIC_RELEASE, __HIP_MEMORY_SCOPE_AGENT);
        unsigned int old = __hip_atomic_fetch_add(ctr, 1u,
                           __ATOMIC_ACQ_REL, __HIP_MEMORY_SCOPE_AGENT);
        lastflag = (old == RB_GRID - 1) ? 1u : 0u;
    }
    __syncthreads();
    if (!lastflag) return;

    // ---- final combine (single block, fixed order -> deterministic) ----
    float v = 0.f;
    if (t < 128) v = w[t >> 4] * farw[t] * 0.125f;
    if (t < 64)
        v += (CDW * 0.125f / K1) * w[t >> 3] *
             __hip_atomic_load(&chbp[t], __ATOMIC_ACQUIRE, __HIP_MEMORY_SCOPE_AGENT);
#pragma unroll
    for (int off = 32; off; off >>= 1) v += __shfl_down(v, off, 64);
    __syncthreads();                 // protect s[] reuse
    if (lane == 0) s[wid] = v;
    __syncthreads();
    if (t == 0) out[0] = s[0] + s[1] + s[2] + s[3];
}

// ---------------------------------------------------------------------------
extern "C" void kernel_launch(void* const* d_in, const int* in_sizes, int n_in,
                              void* d_out, int out_size, void* d_ws, size_t ws_size,
                              hipStream_t stream) {
    const float* adv = (const float*)d_in[0];
    const float* ori = (const float*)d_in[1];
    const float* w   = (const float*)d_in[2];
    float* ws    = (float*)d_ws;
    float* pmins = ws + PMIN_OFF;
    float* farw  = ws + FARW_OFF;
    float* chbp  = ws + CHB_OFF;
    unsigned int* ctr = (unsigned int*)(ws + CTR_OFF);
    float* out   = (float*)d_out;

    fused_a<<<dim3(GRID_A), 256, 0, stream>>>(adv, ori, pmins, farw, ctr);
    reduce_b<<<dim3(RB_GRID), 256, 0, stream>>>(adv, pmins, farw, w, chbp, ctr, out);
}

// Round 17
// 22.279 us; speedup vs baseline: 1.2407x; 1.2407x over previous
//
#include <hip/hip_runtime.h>
#include <float.h>
#include <math.h>

// Problem constants (fixed by reference)
#define NB    8
#define K1    2048
#define K2    8192
#define NADD  16
#define PP    128          // K1 / NUM_ADD
#define FEPS  1e-7f
#define CDW   0.1f

// chamfer: block = (b, abk) covers 32 adv rows x ALL ori of batch b.
// ori staged in 2 phases of 4096 packed points (32 KB LDS).
#define ABK      64                   // blocks per batch (32 rows each)
#define FAR_GRID 64                   // farthest blocks first (cheap, finish early)
#define CH_GRID  (NB * ABK)           // 512
#define GRID_A   (FAR_GRID + CH_GRID) // 576 blocks, all co-resident (32KB LDS)
#define HPTS     4096                 // points per staging phase

// ws layout (float offsets): no pmins, no counters
#define CHP_OFF  0                    // 512 floats
#define FARW_OFF 512                  // 128 floats

typedef __bf16 bf16x8 __attribute__((ext_vector_type(8)));
typedef float  f32x4  __attribute__((ext_vector_type(4)));
typedef unsigned long long u64;

// fp32 -> bf16 bits, round-to-nearest-even (proven in R11-R15, absmax 0)
__device__ __forceinline__ u64 bfbits(float x) {
    union { float f; unsigned int u; } c; c.f = x;
    unsigned int u = c.u;
    u += 0x7fffu + ((u >> 16) & 1u);
    return (u64)(u >> 16);
}
__device__ __forceinline__ u64 pack3(float x, float y, float z) {
    float o2 = fmaf(x, x, fmaf(y, y, z * z));
    return bfbits(x) | (bfbits(y) << 16) | (bfbits(z) << 32) | (bfbits(o2) << 48);
}

// ---------------------------------------------------------------------------
// Kernel A: farthest (blocks 0..63, exact fp32) + MFMA chamfer (64..575).
// Chamfer: acc = sum_k a'_k o'_k, a' = (-2ax,-2ay,-2az,1)/4 replicated in all
// 4 lane-group octets, o' = (ox,oy,oz,|o|^2) -> acc = o^2 - 2 a.o (any K map).
// Wave wv scans its fixed ori quarter; running min over both phases; then
// 16-lane butterfly (cols) + LDS min (waves) + a^2 + clamp + 32-row sum ->
// one partial per block. Zero intermediates beyond chpart[512].
// ---------------------------------------------------------------------------
__global__ __launch_bounds__(256) void fused_a(const float* __restrict__ adv,
                                               const float* __restrict__ ori,
                                               float* __restrict__ chpart,
                                               float* __restrict__ farw) {
    __shared__ u64 so[HPTS];          // 32 KB; far path reuses as float[768]
    __shared__ float smin[4][32];
    __shared__ float sred[4];
    const int bid = blockIdx.x;
    const int t   = threadIdx.x;

    if (bid < FAR_GRID) {
        // ---- farthest: block = (b, cluster-pair), 128 threads per cluster ----
        const int b  = bid >> 3;
        const int cp = bid & 7;
        const int g  = t >> 7;
        const int p  = t & 127;
        const int ci = cp * 2 + g;

        float* sf = (float*)so;        // [2][3][128]
        const float* c = adv + (size_t)(b * K1 + ci * PP) * 3;
        float px = c[p * 3 + 0], py = c[p * 3 + 1], pz = c[p * 3 + 2];
        float* sx = sf + g * 384;
        sx[p] = px; sx[128 + p] = py; sx[256 + p] = pz;
        __syncthreads();

        const float pxm = px - FEPS, pym = py - FEPS, pzm = pz - FEPS;
        float mx = 0.f;
#pragma unroll 8
        for (int q = 0; q < PP; ++q) {
            float dx = sx[q] - pxm;
            float dy = sx[128 + q] - pym;
            float dz = sx[256 + q] - pzm;
            mx = fmaxf(mx, fmaf(dx, dx, fmaf(dy, dy, dz * dz)));
        }
#pragma unroll
        for (int off = 32; off; off >>= 1) mx = fmaxf(mx, __shfl_down(mx, off, 64));
        if ((t & 63) == 0) sred[t >> 6] = mx;
        __syncthreads();
        if (t == 0)   farw[b * NADD + cp * 2 + 0] = sqrtf(fmaxf(sred[0], sred[1]));
        if (t == 128) farw[b * NADD + cp * 2 + 1] = sqrtf(fmaxf(sred[2], sred[3]));
    } else {
        // ---- chamfer: block = (b, abk); rows rowb..rowb+31 vs all ori(b) ----
        const int cb   = bid - FAR_GRID;
        const int abk  = cb & (ABK - 1);
        const int b    = cb >> 6;
        const int lane = t & 63;
        const int wv   = t >> 6;
        const int rowb = abk * 32;

        // A fragments: row = lane&15 replicated across 4 lane-groups, /4 scale
        const float* a0 = adv + ((size_t)b * K1 + rowb + (lane & 15)) * 3;
        const float* a1 = a0 + 48;                  // +16 rows
        const u64 q25 = 0x3e80ULL << 48;            // bf16(0.25) in slot 3
        u64 pk0 = bfbits(-0.5f * a0[0]) | (bfbits(-0.5f * a0[1]) << 16)
                | (bfbits(-0.5f * a0[2]) << 32) | q25;
        u64 pk1 = bfbits(-0.5f * a1[0]) | (bfbits(-0.5f * a1[1]) << 16)
                | (bfbits(-0.5f * a1[2]) << 32) | q25;
        const bf16x8 af0 = __builtin_bit_cast(bf16x8, make_ulonglong2(pk0, 0ULL));
        const bf16x8 af1 = __builtin_bit_cast(bf16x8, make_ulonglong2(pk1, 0ULL));

        const f32x4 z4 = {0.f, 0.f, 0.f, 0.f};
        f32x4 m0 = {FLT_MAX, FLT_MAX, FLT_MAX, FLT_MAX};
        f32x4 m1 = m0;

        for (int h = 0; h < 2; ++h) {
            // stage 4096 points as packed bf16x4 [x,y,z,o2]; 16 pts/thread
            // (4 groups of 4 consecutive points = 3 float4 loads each)
            const float4* f4 = (const float4*)ori + ((size_t)b * 6144 + h * 3072);
#pragma unroll
            for (int i = 0; i < 4; ++i) {
                const int pg = i * 256 + t;        // 4-point group 0..1023
                float4 f0 = f4[pg * 3 + 0];
                float4 f1 = f4[pg * 3 + 1];
                float4 f2 = f4[pg * 3 + 2];
                u64 w0 = pack3(f0.x, f0.y, f0.z);
                u64 w1 = pack3(f0.w, f1.x, f1.y);
                u64 w2 = pack3(f1.z, f1.w, f2.x);
                u64 w3 = pack3(f2.y, f2.z, f2.w);
                ulonglong2* dst = (ulonglong2*)&so[pg * 4];
                dst[0] = make_ulonglong2(w0, w1);
                dst[1] = make_ulonglong2(w2, w3);
            }
            __syncthreads();

            // this wave's fixed quarter: 1024 pts = 64 tiles of 16
#pragma unroll 4
            for (int tl = 0; tl < 64; ++tl) {
                u64 lo = so[wv * 1024 + tl * 16 + (lane & 15)];  // 4-way bcast
                bf16x8 bf = __builtin_bit_cast(bf16x8, make_ulonglong2(lo, 0ULL));
                f32x4 acc0 = __builtin_amdgcn_mfma_f32_16x16x32_bf16(af0, bf, z4, 0, 0, 0);
                f32x4 acc1 = __builtin_amdgcn_mfma_f32_16x16x32_bf16(af1, bf, z4, 0, 0, 0);
#pragma unroll
                for (int r = 0; r < 4; ++r) {
                    m0[r] = fminf(m0[r], acc0[r]);
                    m1[r] = fminf(m1[r], acc1[r]);
                }
            }
            __syncthreads();               // all waves done before restage
        }

        // C layout: col = lane&15 (ori), row = (lane>>4)*4 + reg (adv).
        // min over cols: butterfly within 16-lane groups
#pragma unroll
        for (int r = 0; r < 4; ++r) {
            float v0 = m0[r], v1 = m1[r];
#pragma unroll
            for (int msk = 1; msk < 16; msk <<= 1) {
                v0 = fminf(v0, __shfl_xor(v0, msk, 64));
                v1 = fminf(v1, __shfl_xor(v1, msk, 64));
            }
            if ((lane & 15) == 0) {
                const int rr = (lane >> 4) * 4 + r;
                smin[wv][rr]      = v0;
                smin[wv][16 + rr] = v1;
            }
        }
        __syncthreads();

        // cross-wave min + a^2 + clamp + sum over the block's 32 rows
        if (t < 64) {
            float sum = 0.f;
            if (t < 32) {
                float mm = fminf(fminf(smin[0][t], smin[1][t]),
                                 fminf(smin[2][t], smin[3][t]));
                const float* a = adv + ((size_t)b * K1 + rowb + t) * 3;
                float a2 = fmaf(a[0], a[0], fmaf(a[1], a[1], a[2] * a[2]));
                sum = fmaxf(a2 + mm, 0.f);
            }
#pragma unroll
            for (int off = 32; off; off >>= 1) sum += __shfl_down(sum, off, 64);
            if (t == 0) chpart[cb] = sum;   // cb = b*64 + abk
        }
    }
}

// ---------------------------------------------------------------------------
// Kernel B: single block, fixed-order weighted combine of 512+128 partials.
// ---------------------------------------------------------------------------
__global__ __launch_bounds__(256) void combine_b(const float* __restrict__ chpart,
                                                 const float* __restrict__ farw,
                                                 const float* __restrict__ w,
                                                 float* __restrict__ out) {
    __shared__ float s[4];
    const int t = threadIdx.x;
    const float c1 = CDW * 0.125f / K1;
    // chpart[e]: b = e>>6 ; thread t handles e=t and e=t+256
    float v = c1 * (w[t >> 6] * chpart[t] + w[(t >> 6) + 4] * chpart[t + 256]);
    if (t < 128) v += 0.125f * w[t >> 4] * farw[t];
#pragma unroll
    for (int off = 32; off; off >>= 1) v += __shfl_down(v, off, 64);
    if ((t & 63) == 0) s[t >> 6] = v;
    __syncthreads();
    if (t == 0) out[0] = s[0] + s[1] + s[2] + s[3];
}

// ---------------------------------------------------------------------------
extern "C" void kernel_launch(void* const* d_in, const int* in_sizes, int n_in,
                              void* d_out, int out_size, void* d_ws, size_t ws_size,
                              hipStream_t stream) {
    const float* adv = (const float*)d_in[0];
    const float* ori = (const float*)d_in[1];
    const float* w   = (const float*)d_in[2];
    float* ws     = (float*)d_ws;
    float* chpart = ws + CHP_OFF;
    float* farw   = ws + FARW_OFF;
    float* out    = (float*)d_out;

    fused_a<<<dim3(GRID_A), 256, 0, stream>>>(adv, ori, chpart, farw);
    combine_b<<<dim3(1), 256, 0, stream>>>(chpart, farw, w, out);
}